// Round 4
// baseline (13.211 us; speedup 1.0000x reference)
//
#include <hip/hip_runtime.h>

// Problem: B=128, L=98, H=64, W=64. Only channels 96/97 matter.
// out[0]            = eye_loss (scalar)
// out[1   .. 512]   = source_eyes [128,4]  (lm96_x, lm96_y, lm97_x, lm97_y)
// out[513 .. 1024]  = target_eyes [128,4]
//
// Single-dispatch design: 256 blocks (one per (b, eye-channel)) x 512 threads
// (8 waves/CU for latency hiding; each thread loads 2 float4 per tensor).
// Each block publishes its squared-error partial into d_ws as a
// self-validating pair (P, P+1.0f) with agent-scope release. Block 0
// acquire-spins until all 256 pairs are consistent, then does a
// deterministic tree sum -> out[0]. Poison (0xAAAAAAAA) fails the pair
// check, so the spinner can't false-pass on poisoned ws. Writers never wait
// on the reader -> deadlock-free under any block scheduling.

#define HW 4096          // 64*64
#define LCH 98
#define INV_CNT (1.0f / 524288.0f)   // 1/(128*64*64)

__device__ __forceinline__ void compute_eye(const float* hm, int idx,
                                            float* ox, float* oy) {
    int px = idx & 63;
    int py = idx >> 6;
    auto gather = [&](int dx, int dy) -> float {
        int x = min(max(px + dx, 0), 63);
        int y = min(max(py + dy, 0), 63);
        return hm[y * 64 + x];
    };
    float dxv = gather(1, 0) - gather(-1, 0);
    float dyv = gather(0, 1) - gather(0, -1);
    bool inside = (px > 0) && (px < 63) && (py > 0) && (py < 63);
    float offx = inside ? (dxv > 0.0f ? 0.25f : (dxv < 0.0f ? -0.25f : 0.0f)) : 0.0f;
    float offy = inside ? (dyv > 0.0f ? 0.25f : (dyv < 0.0f ? -0.25f : 0.0f)) : 0.0f;
    *ox = ((float)px + 0.5f + offx) * 4.0f;   // (px + 1 + off - 0.5) * 4
    *oy = ((float)py + 0.5f + offy) * 4.0f;
}

__global__ __launch_bounds__(512)
void eye_loss_onenode(const float* __restrict__ src,
                      const float* __restrict__ tgt,
                      float* __restrict__ out,
                      float* __restrict__ ws) {
    const int tid = threadIdx.x;         // 0..511
    const int bid = blockIdx.x;          // 0..255
    const int b = bid >> 1;              // batch
    const int l = bid & 1;               // 0 -> ch96, 1 -> ch97
    const size_t base = ((size_t)b * LCH + 96 + l) * HW;
    const float* sch = src + base;
    const float* tch = tgt + base;

    // per-thread scan: 2 float4 loads per tensor, increasing index order
    float sBestV = -INFINITY, tBestV = -INFINITY;
    int   sBestI = 0, tBestI = 0;
    float lsum = 0.0f;

    #pragma unroll
    for (int k = 0; k < 2; ++k) {
        int e = (k * 512 + tid) * 4;     // element index, coalesced float4
        float4 s = *(const float4*)(sch + e);
        float4 t = *(const float4*)(tch + e);
        float sv[4] = {s.x, s.y, s.z, s.w};
        float tv[4] = {t.x, t.y, t.z, t.w};
        #pragma unroll
        for (int c = 0; c < 4; ++c) {
            float d = sv[c] - tv[c];
            lsum += d * d;
            if (sv[c] > sBestV) { sBestV = sv[c]; sBestI = e + c; }  // strict >: first max wins
            if (tv[c] > tBestV) { tBestV = tv[c]; tBestI = e + c; }
        }
    }

    // wave64 butterfly reductions (argmax with min-index tiebreak, and sum)
    #pragma unroll
    for (int off = 32; off > 0; off >>= 1) {
        float v = __shfl_down(sBestV, off);
        int   i = __shfl_down(sBestI, off);
        if (v > sBestV || (v == sBestV && i < sBestI)) { sBestV = v; sBestI = i; }
        v = __shfl_down(tBestV, off);
        i = __shfl_down(tBestI, off);
        if (v > tBestV || (v == tBestV && i < tBestI)) { tBestV = v; tBestI = i; }
        lsum += __shfl_down(lsum, off);
    }

    __shared__ float wv_s[8], wv_t[8], wsum[8];
    __shared__ int   wi_s[8], wi_t[8];
    const int wave = tid >> 6;
    if ((tid & 63) == 0) {
        wv_s[wave] = sBestV; wi_s[wave] = sBestI;
        wv_t[wave] = tBestV; wi_t[wave] = tBestI;
        wsum[wave] = lsum;
    }
    __syncthreads();

    if (tid == 0) {
        float bs = wv_s[0]; int bsi = wi_s[0];
        float bt = wv_t[0]; int bti = wi_t[0];
        float total = wsum[0];
        #pragma unroll
        for (int w = 1; w < 8; ++w) {
            if (wv_s[w] > bs || (wv_s[w] == bs && wi_s[w] < bsi)) { bs = wv_s[w]; bsi = wi_s[w]; }
            if (wv_t[w] > bt || (wv_t[w] == bt && wi_t[w] < bti)) { bt = wv_t[w]; bti = wi_t[w]; }
            total += wsum[w];
        }
        float x, y;
        compute_eye(sch, bsi, &x, &y);
        out[1 + b * 4 + l * 2 + 0] = x;
        out[1 + b * 4 + l * 2 + 1] = y;
        compute_eye(tch, bti, &x, &y);
        out[513 + b * 4 + l * 2 + 0] = x;
        out[513 + b * 4 + l * 2 + 1] = y;

        // publish partial as self-validating pair with agent-scope release
        ws[bid] = total;
        __hip_atomic_store(&ws[256 + bid], total + 1.0f,
                           __ATOMIC_RELEASE, __HIP_MEMORY_SCOPE_AGENT);
    }

    // block 0: gather all 256 partials, deterministic tree sum -> out[0]
    if (bid == 0) {
        __syncthreads();   // our own pair is written before spinning
        float a = 0.0f;
        if (tid < 256) {
            for (;;) {
                float fb = __hip_atomic_load(&ws[256 + tid],
                                             __ATOMIC_ACQUIRE, __HIP_MEMORY_SCOPE_AGENT);
                a = __hip_atomic_load(&ws[tid],
                                      __ATOMIC_RELAXED, __HIP_MEMORY_SCOPE_AGENT);
                if (fb == a + 1.0f) break;
                __builtin_amdgcn_s_sleep(2);
            }
        }
        // sum across all 8 waves (waves 4..7 contribute 0)
        #pragma unroll
        for (int off = 32; off > 0; off >>= 1) a += __shfl_down(a, off);
        __shared__ float fs[8];
        if ((tid & 63) == 0) fs[tid >> 6] = a;
        __syncthreads();
        if (tid == 0) {
            float v = 0.0f;
            #pragma unroll
            for (int w = 0; w < 8; ++w) v += fs[w];
            out[0] = v * INV_CNT;
        }
    }
}

extern "C" void kernel_launch(void* const* d_in, const int* in_sizes, int n_in,
                              void* d_out, int out_size, void* d_ws, size_t ws_size,
                              hipStream_t stream) {
    const float* src = (const float*)d_in[0];
    const float* tgt = (const float*)d_in[1];
    float* out = (float*)d_out;
    float* ws  = (float*)d_ws;

    eye_loss_onenode<<<256, 512, 0, stream>>>(src, tgt, out, ws);
}

// Round 5
// 12.694 us; speedup vs baseline: 1.0408x; 1.0408x over previous
//
#include <hip/hip_runtime.h>

// Problem: B=128, L=98, H=64, W=64. Only channels 96/97 matter.
// out[0]            = eye_loss (scalar)
// out[1   .. 512]   = source_eyes [128,4]  (lm96_x, lm96_y, lm97_x, lm97_y)
// out[513 .. 1024]  = target_eyes [128,4]
//
// Single-dispatch design: 256 blocks (one per (b, eye-channel)) x 256 threads.
// Best-measured config (R3: 12.85us; R4's 512-thread variant: 13.21us).
// Each block publishes its squared-error partial into d_ws as a
// self-validating pair (P, P+1.0f) with agent-scope release. Block 0
// acquire-spins until all 256 pairs are consistent, then does a
// deterministic tree sum -> out[0]. Poison (0xAAAAAAAA) fails the pair
// check, so the spinner can't false-pass on poisoned ws. Writers never wait
// on the reader -> deadlock-free under any block scheduling.
// Time budget: ~8 MB unique fetch ~= 1.3us at HBM ceiling; measured 12.85us
// => dominated by single-node graph-replay/dispatch overhead (launch floor).

#define HW 4096          // 64*64
#define LCH 98
#define INV_CNT (1.0f / 524288.0f)   // 1/(128*64*64)

__device__ __forceinline__ void compute_eye(const float* hm, int idx,
                                            float* ox, float* oy) {
    int px = idx & 63;
    int py = idx >> 6;
    auto gather = [&](int dx, int dy) -> float {
        int x = min(max(px + dx, 0), 63);
        int y = min(max(py + dy, 0), 63);
        return hm[y * 64 + x];
    };
    float dxv = gather(1, 0) - gather(-1, 0);
    float dyv = gather(0, 1) - gather(0, -1);
    bool inside = (px > 0) && (px < 63) && (py > 0) && (py < 63);
    float offx = inside ? (dxv > 0.0f ? 0.25f : (dxv < 0.0f ? -0.25f : 0.0f)) : 0.0f;
    float offy = inside ? (dyv > 0.0f ? 0.25f : (dyv < 0.0f ? -0.25f : 0.0f)) : 0.0f;
    *ox = ((float)px + 0.5f + offx) * 4.0f;   // (px + 1 + off - 0.5) * 4
    *oy = ((float)py + 0.5f + offy) * 4.0f;
}

__global__ __launch_bounds__(256)
void eye_loss_onenode(const float* __restrict__ src,
                      const float* __restrict__ tgt,
                      float* __restrict__ out,
                      float* __restrict__ ws) {
    const int tid = threadIdx.x;
    const int bid = blockIdx.x;          // 0..255
    const int b = bid >> 1;              // batch
    const int l = bid & 1;               // 0 -> ch96, 1 -> ch97
    const size_t base = ((size_t)b * LCH + 96 + l) * HW;
    const float* sch = src + base;
    const float* tch = tgt + base;

    // per-thread scan: 4 float4 loads each of src & tgt, increasing index order
    float sBestV = -INFINITY, tBestV = -INFINITY;
    int   sBestI = 0, tBestI = 0;
    float lsum = 0.0f;

    #pragma unroll
    for (int k = 0; k < 4; ++k) {
        int e = (k * 256 + tid) * 4;     // element index, coalesced float4
        float4 s = *(const float4*)(sch + e);
        float4 t = *(const float4*)(tch + e);
        float sv[4] = {s.x, s.y, s.z, s.w};
        float tv[4] = {t.x, t.y, t.z, t.w};
        #pragma unroll
        for (int c = 0; c < 4; ++c) {
            float d = sv[c] - tv[c];
            lsum += d * d;
            if (sv[c] > sBestV) { sBestV = sv[c]; sBestI = e + c; }  // strict >: first max wins
            if (tv[c] > tBestV) { tBestV = tv[c]; tBestI = e + c; }
        }
    }

    // wave64 butterfly reductions (argmax with min-index tiebreak, and sum)
    #pragma unroll
    for (int off = 32; off > 0; off >>= 1) {
        float v = __shfl_down(sBestV, off);
        int   i = __shfl_down(sBestI, off);
        if (v > sBestV || (v == sBestV && i < sBestI)) { sBestV = v; sBestI = i; }
        v = __shfl_down(tBestV, off);
        i = __shfl_down(tBestI, off);
        if (v > tBestV || (v == tBestV && i < tBestI)) { tBestV = v; tBestI = i; }
        lsum += __shfl_down(lsum, off);
    }

    __shared__ float wv_s[4], wv_t[4], wsum[4];
    __shared__ int   wi_s[4], wi_t[4];
    const int wave = tid >> 6;
    if ((tid & 63) == 0) {
        wv_s[wave] = sBestV; wi_s[wave] = sBestI;
        wv_t[wave] = tBestV; wi_t[wave] = tBestI;
        wsum[wave] = lsum;
    }
    __syncthreads();

    if (tid == 0) {
        float bs = wv_s[0]; int bsi = wi_s[0];
        float bt = wv_t[0]; int bti = wi_t[0];
        float total = wsum[0];
        #pragma unroll
        for (int w = 1; w < 4; ++w) {
            if (wv_s[w] > bs || (wv_s[w] == bs && wi_s[w] < bsi)) { bs = wv_s[w]; bsi = wi_s[w]; }
            if (wv_t[w] > bt || (wv_t[w] == bt && wi_t[w] < bti)) { bt = wv_t[w]; bti = wi_t[w]; }
            total += wsum[w];
        }
        float x, y;
        compute_eye(sch, bsi, &x, &y);
        out[1 + b * 4 + l * 2 + 0] = x;
        out[1 + b * 4 + l * 2 + 1] = y;
        compute_eye(tch, bti, &x, &y);
        out[513 + b * 4 + l * 2 + 0] = x;
        out[513 + b * 4 + l * 2 + 1] = y;

        // publish partial as self-validating pair with agent-scope release
        ws[bid] = total;
        __hip_atomic_store(&ws[256 + bid], total + 1.0f,
                           __ATOMIC_RELEASE, __HIP_MEMORY_SCOPE_AGENT);
    }

    // block 0: gather all 256 partials, deterministic tree sum -> out[0]
    if (bid == 0) {
        __syncthreads();   // ensure our own pair is written before spinning
        float a;
        for (;;) {
            float fb = __hip_atomic_load(&ws[256 + tid],
                                         __ATOMIC_ACQUIRE, __HIP_MEMORY_SCOPE_AGENT);
            a = __hip_atomic_load(&ws[tid],
                                  __ATOMIC_RELAXED, __HIP_MEMORY_SCOPE_AGENT);
            if (fb == a + 1.0f) break;
            __builtin_amdgcn_s_sleep(2);
        }
        float v = a;
        #pragma unroll
        for (int off = 32; off > 0; off >>= 1) v += __shfl_down(v, off);
        __shared__ float fs[4];
        if ((tid & 63) == 0) fs[tid >> 6] = v;
        __syncthreads();
        if (tid == 0) out[0] = (fs[0] + fs[1] + fs[2] + fs[3]) * INV_CNT;
    }
}

extern "C" void kernel_launch(void* const* d_in, const int* in_sizes, int n_in,
                              void* d_out, int out_size, void* d_ws, size_t ws_size,
                              hipStream_t stream) {
    const float* src = (const float*)d_in[0];
    const float* tgt = (const float*)d_in[1];
    float* out = (float*)d_out;
    float* ws  = (float*)d_ws;

    eye_loss_onenode<<<256, 256, 0, stream>>>(src, tgt, out, ws);
}